// Round 9
// baseline (409.695 us; speedup 1.0000x reference)
//
#include <hip/hip_runtime.h>
#include <math.h>

#define N_NODES 50000
#define N_EDGES 400000
#define M_PAD 50048
#define NFEAT 512
#define NHID 256
#define NCLASS 8
#define SCAN_BLOCKS ((N_NODES + 255) / 256)   // 196

typedef unsigned short u16;
typedef __attribute__((ext_vector_type(8))) unsigned short u16x8;
typedef __attribute__((ext_vector_type(8))) short s16x8;
typedef __attribute__((ext_vector_type(4))) float f32x4;

__device__ __forceinline__ float bf2f(u16 u) {
    union { unsigned int i; float f; } v; v.i = ((unsigned int)u) << 16; return v.f;
}
__device__ __forceinline__ float bf2f_hi(unsigned int packed) {
    union { unsigned int i; float f; } v; v.i = packed & 0xffff0000u; return v.f;
}
__device__ __forceinline__ float bf2f_lo(unsigned int packed) {
    union { unsigned int i; float f; } v; v.i = packed << 16; return v.f;
}
__device__ __forceinline__ u16 f2bf(float f) {
    union { float f; unsigned int i; } v; v.f = f;
    unsigned int r = v.i + 0x7fffu + ((v.i >> 16) & 1u);
    return (u16)(r >> 16);
}

// ---------------- prep: degrees, CSR ----------------

__global__ void init_k(float* deg, int* cnt, int* cur) {
    int i = blockIdx.x * blockDim.x + threadIdx.x;
    if (i < N_NODES) { deg[i] = 1.0f; cnt[i] = 0; cur[i] = 0; }
}

__global__ void edge_deg_k(const float* __restrict__ p, const int* __restrict__ dst,
                           float* __restrict__ deg, int* __restrict__ cnt,
                           float* __restrict__ ew_out) {
    int e = blockIdx.x * blockDim.x + threadIdx.x;
    if (e >= N_EDGES) return;
    float ew = 1.0f / (1.0f + expf(-p[e]));
    ew_out[e] = ew;
    int d = dst[e];
    atomicAdd(&deg[d], ew);
    atomicAdd(&cnt[d], 1);
}

__global__ void finalize_dinv_k(float* __restrict__ deg, const int* __restrict__ cnt,
                                float* __restrict__ dinv3) {
    int i = blockIdx.x * blockDim.x + threadIdx.x;
    if (i < N_NODES) {
        deg[i]   = 1.0f / sqrtf(deg[i]);
        dinv3[i] = 1.0f / sqrtf(1.0f + (float)cnt[i]);
    }
}

__global__ __launch_bounds__(256) void scan1_k(const int* __restrict__ cnt,
                                               int* __restrict__ row_start,
                                               int* __restrict__ bsum) {
    __shared__ int tmp[256];
    int t = threadIdx.x;
    int g = blockIdx.x * 256 + t;
    int v = (g < N_NODES) ? cnt[g] : 0;
    tmp[t] = v;
    __syncthreads();
    #pragma unroll
    for (int off = 1; off < 256; off <<= 1) {
        int u = (t >= off) ? tmp[t - off] : 0;
        __syncthreads();
        tmp[t] += u;
        __syncthreads();
    }
    if (g < N_NODES) row_start[g] = tmp[t] - v;
    if (t == 255) bsum[blockIdx.x] = tmp[255];
}

__global__ __launch_bounds__(256) void scan2_k(int* __restrict__ bsum) {
    __shared__ int tmp[256];
    int t = threadIdx.x;
    int v = (t < SCAN_BLOCKS) ? bsum[t] : 0;
    tmp[t] = v;
    __syncthreads();
    #pragma unroll
    for (int off = 1; off < 256; off <<= 1) {
        int u = (t >= off) ? tmp[t - off] : 0;
        __syncthreads();
        tmp[t] += u;
        __syncthreads();
    }
    if (t < SCAN_BLOCKS) bsum[t] = tmp[t] - v;
}

__global__ __launch_bounds__(256) void scan3_k(int* __restrict__ row_start,
                                               const int* __restrict__ bsum) {
    int t = threadIdx.x;
    int g = blockIdx.x * 256 + t;
    if (g < N_NODES) row_start[g] += bsum[blockIdx.x];
    if (g == 0) row_start[N_NODES] = N_EDGES;
}

__global__ void fill_k(const int* __restrict__ src, const int* __restrict__ dst,
                       const float* __restrict__ ew, const float* __restrict__ dinv,
                       const float* __restrict__ dinv3,
                       const int* __restrict__ row_start, int* __restrict__ cur,
                       uint2* __restrict__ ep, uint2* __restrict__ ep3) {
    int e = blockIdx.x * blockDim.x + threadIdx.x;
    if (e >= N_EDGES) return;
    int s = src[e], d = dst[e];
    float w  = dinv[s] * ew[e] * dinv[d];
    float w3 = dinv3[s] * dinv3[d];
    int p = atomicAdd(&cur[d], 1);
    int slot = row_start[d] + p;
    ep[slot]  = make_uint2((unsigned int)s, __float_as_uint(w));
    ep3[slot] = make_uint2((unsigned int)s, __float_as_uint(w3));
}

// ---------------- weight transpose: W fp32 [K][256] -> Wt bf16 [256][K] ----------------

__global__ void wtrans_all_k(const float* __restrict__ W1, const float* __restrict__ W2,
                             const float* __restrict__ W3, u16* __restrict__ wt1,
                             u16* __restrict__ wt2, u16* __restrict__ wt3) {
    int idx = blockIdx.x * 256 + threadIdx.x;
    const float* W; u16* Wt; int K;
    if (idx < 256 * 512)           { W = W1; Wt = wt1; K = 512; }
    else if (idx < 256 * 512 + 256 * 256) { idx -= 256 * 512; W = W2; Wt = wt2; K = 256; }
    else if (idx < 256 * 512 + 2 * 256 * 256) { idx -= 256 * 512 + 256 * 256; W = W3; Wt = wt3; K = 256; }
    else return;
    int n = idx / K, k = idx - n * K;
    Wt[(size_t)n * K + k] = f2bf(W[(size_t)k * 256 + n]);
}

__global__ void zeropad_k(u16* a, u16* b) {
    int i = blockIdx.x * 256 + threadIdx.x;
    if (i < (M_PAD - N_NODES) * 256) {
        a[(size_t)N_NODES * 256 + i] = 0;
        b[(size_t)N_NODES * 256 + i] = 0;
    }
}

// ---------------- barrier-free register GEMM: C[M_PAD x 256] = A @ BT^T ----------------
// 1 wave per block, 32x64 output tile -> grid (4, 1564) = 6256 waves (24/CU).
// Depth-1 software prefetch (two named register sets). No LDS, no barriers.
// AF32: layer-1 A is fp32, converted in registers (pad rows read as 0).

__device__ __forceinline__ u16x8 ldcvt_f32(const float* p, bool ok) {
    u16x8 o = {0, 0, 0, 0, 0, 0, 0, 0};
    if (ok) {
        float4 a = *(const float4*)p;
        float4 b = *(const float4*)(p + 4);
        o[0] = f2bf(a.x); o[1] = f2bf(a.y); o[2] = f2bf(a.z); o[3] = f2bf(a.w);
        o[4] = f2bf(b.x); o[5] = f2bf(b.y); o[6] = f2bf(b.z); o[7] = f2bf(b.w);
    }
    return o;
}

#define LOADF(AV, BV, T)                                                        \
    do {                                                                        \
        _Pragma("unroll")                                                       \
        for (int m = 0; m < 2; ++m) {                                           \
            if constexpr (AF32) AV[m] = (s16x8)ldcvt_f32(ap32[m] + (T) * 32, ok[m]); \
            else                AV[m] = *(const s16x8*)(ap16[m] + (T) * 32);    \
        }                                                                       \
        _Pragma("unroll")                                                       \
        for (int n = 0; n < 4; ++n)                                             \
            BV[n] = *(const s16x8*)(bp[n] + (T) * 32);                          \
    } while (0)

#define MFMAF(AV, BV)                                                           \
    do {                                                                        \
        _Pragma("unroll")                                                       \
        for (int m = 0; m < 2; ++m)                                             \
            _Pragma("unroll")                                                   \
            for (int n = 0; n < 4; ++n)                                         \
                acc[m][n] = __builtin_amdgcn_mfma_f32_16x16x32_bf16(AV[m], BV[n], acc[m][n], 0, 0, 0); \
    } while (0)

template <bool AF32, int MINW>
__global__ __launch_bounds__(64, MINW) void gemm_rr_k(const void* __restrict__ Ap,
                                                      const u16* __restrict__ BT,
                                                      u16* __restrict__ C, int K) {
    int lane = threadIdx.x;            // 0..63
    int row0 = blockIdx.y * 32;
    int col0 = blockIdx.x * 64;
    const u16*   A16 = (const u16*)Ap;
    const float* A32 = (const float*)Ap;

    int fr = lane & 15;                // fragment row (A) / col (B)
    int kb = (lane >> 4) << 3;         // k-elem offset within 32-chunk

    const u16* ap16[2]; const float* ap32[2]; bool ok[2];
    #pragma unroll
    for (int m = 0; m < 2; ++m) {
        int gr = row0 + m * 16 + fr;
        ok[m]   = gr < N_NODES;
        ap16[m] = A16 + (size_t)gr * K + kb;
        ap32[m] = A32 + (size_t)gr * K + kb;
    }
    const u16* bp[4];
    #pragma unroll
    for (int n = 0; n < 4; ++n)
        bp[n] = BT + (size_t)(col0 + n * 16 + fr) * K + kb;

    f32x4 acc[2][4] = {};
    s16x8 a0[2], b0[4], a1[2], b1[4];

    int nt = K >> 5;                   // BK = 32; nt is even (16 or 8)
    LOADF(a0, b0, 0);
    for (int t = 0; t < nt; t += 2) {
        LOADF(a1, b1, t + 1);
        MFMAF(a0, b0);
        if (t + 2 < nt) LOADF(a0, b0, t + 2);
        MFMAF(a1, b1);
    }

    // C/D layout: col = lane&15, row = (lane>>4)*4 + r
    int crow0 = row0 + ((lane >> 4) << 2);
    int ccol  = col0 + fr;
    #pragma unroll
    for (int m = 0; m < 2; ++m)
        #pragma unroll
        for (int n = 0; n < 4; ++n)
            #pragma unroll
            for (int r = 0; r < 4; ++r)
                C[(size_t)(crow0 + m * 16 + r) * 256 + ccol + n * 16] = f2bf(acc[m][n][r]);
}

// ---------------- gather (bf16 in/out), edge loop unrolled x4 ----------------

template <bool RELU>
__global__ __launch_bounds__(256) void gather_k(const u16* __restrict__ h,
                                                const int* __restrict__ row_start,
                                                const uint2* __restrict__ ep,
                                                const float* __restrict__ dinv,
                                                const float* __restrict__ bias,
                                                u16* __restrict__ outb) {
    int node = blockIdx.x * 4 + (threadIdx.x >> 6);
    if (node >= N_NODES) return;
    int lane = threadIdx.x & 63;

    float di = dinv[node];
    float sw = di * di;
    uint2 hv = *(const uint2*)(h + (size_t)node * 256 + lane * 4);
    float4 acc;
    acc.x = bf2f_lo(hv.x) * sw; acc.y = bf2f_hi(hv.x) * sw;
    acc.z = bf2f_lo(hv.y) * sw; acc.w = bf2f_hi(hv.y) * sw;

    int beg = row_start[node], end = row_start[node + 1];
    int j = beg;
    for (; j + 4 <= end; j += 4) {
        uint2 e0 = ep[j], e1 = ep[j + 1], e2 = ep[j + 2], e3 = ep[j + 3];
        uint2 u0 = *(const uint2*)(h + (size_t)e0.x * 256 + lane * 4);
        uint2 u1 = *(const uint2*)(h + (size_t)e1.x * 256 + lane * 4);
        uint2 u2 = *(const uint2*)(h + (size_t)e2.x * 256 + lane * 4);
        uint2 u3 = *(const uint2*)(h + (size_t)e3.x * 256 + lane * 4);
        float w0 = __uint_as_float(e0.y), w1 = __uint_as_float(e1.y);
        float w2 = __uint_as_float(e2.y), w3 = __uint_as_float(e3.y);
        acc.x += bf2f_lo(u0.x) * w0; acc.y += bf2f_hi(u0.x) * w0;
        acc.z += bf2f_lo(u0.y) * w0; acc.w += bf2f_hi(u0.y) * w0;
        acc.x += bf2f_lo(u1.x) * w1; acc.y += bf2f_hi(u1.x) * w1;
        acc.z += bf2f_lo(u1.y) * w1; acc.w += bf2f_hi(u1.y) * w1;
        acc.x += bf2f_lo(u2.x) * w2; acc.y += bf2f_hi(u2.x) * w2;
        acc.z += bf2f_lo(u2.y) * w2; acc.w += bf2f_hi(u2.y) * w2;
        acc.x += bf2f_lo(u3.x) * w3; acc.y += bf2f_hi(u3.x) * w3;
        acc.z += bf2f_lo(u3.y) * w3; acc.w += bf2f_hi(u3.y) * w3;
    }
    for (; j < end; ++j) {
        uint2 e = ep[j];
        float w = __uint_as_float(e.y);
        uint2 uv = *(const uint2*)(h + (size_t)e.x * 256 + lane * 4);
        acc.x += bf2f_lo(uv.x) * w; acc.y += bf2f_hi(uv.x) * w;
        acc.z += bf2f_lo(uv.y) * w; acc.w += bf2f_hi(uv.y) * w;
    }
    float4 bv = ((const float4*)bias)[lane];
    acc.x += bv.x; acc.y += bv.y; acc.z += bv.z; acc.w += bv.w;
    if (RELU) {
        acc.x = fmaxf(acc.x, 0.f); acc.y = fmaxf(acc.y, 0.f);
        acc.z = fmaxf(acc.z, 0.f); acc.w = fmaxf(acc.w, 0.f);
    }
    uint2 o;
    o.x = (unsigned int)f2bf(acc.x) | ((unsigned int)f2bf(acc.y) << 16);
    o.y = (unsigned int)f2bf(acc.z) | ((unsigned int)f2bf(acc.w) << 16);
    *(uint2*)(outb + (size_t)node * 256 + lane * 4) = o;
}

// ---------------- final linear + log_softmax ----------------

template <bool FIRST>
__global__ __launch_bounds__(256) void logits_acc_k(const u16* __restrict__ x,
                                                    const float* __restrict__ Wlin,
                                                    const float* __restrict__ blin,
                                                    float* __restrict__ logits, int seg) {
    __shared__ float Ws[256 * 8];
    int tid = threadIdx.x;
    const float* Wseg = Wlin + (size_t)seg * 256 * 8;
    for (int i = tid; i < 2048; i += 256) Ws[i] = Wseg[i];
    __syncthreads();
    int row = blockIdx.x * 32 + (tid >> 3);
    int c = tid & 7;
    if (row >= N_NODES) return;
    const u16* xr = x + (size_t)row * 256;
    float acc = 0.f;
    for (int k8 = 0; k8 < 32; ++k8) {
        u16x8 v = *(const u16x8*)&xr[k8 * 8];
        #pragma unroll
        for (int i = 0; i < 8; ++i) acc += bf2f(v[i]) * Ws[(k8 * 8 + i) * 8 + c];
    }
    float* lp = &logits[(size_t)row * 8 + c];
    if (FIRST) *lp = acc + blin[c];
    else       *lp += acc;
}

__global__ void log_softmax_k(const float* __restrict__ logits, float* __restrict__ out) {
    int row = blockIdx.x * blockDim.x + threadIdx.x;
    if (row >= N_NODES) return;
    float4 a = *(const float4*)&logits[(size_t)row * 8];
    float4 b = *(const float4*)&logits[(size_t)row * 8 + 4];
    float m = fmaxf(fmaxf(fmaxf(a.x, a.y), fmaxf(a.z, a.w)),
                    fmaxf(fmaxf(b.x, b.y), fmaxf(b.z, b.w)));
    float s = expf(a.x - m) + expf(a.y - m) + expf(a.z - m) + expf(a.w - m)
            + expf(b.x - m) + expf(b.y - m) + expf(b.z - m) + expf(b.w - m);
    float ls = logf(s) + m;
    float* o = &out[(size_t)row * 8];
    o[0] = a.x - ls; o[1] = a.y - ls; o[2] = a.z - ls; o[3] = a.w - ls;
    o[4] = b.x - ls; o[5] = b.y - ls; o[6] = b.z - ls; o[7] = b.w - ls;
}

// ---------------- driver ----------------

extern "C" void kernel_launch(void* const* d_in, const int* in_sizes, int n_in,
                              void* d_out, int out_size, void* d_ws, size_t ws_size,
                              hipStream_t stream) {
    const float* x    = (const float*)d_in[0];
    const int*   ei   = (const int*)d_in[1];
    const float* ewp  = (const float*)d_in[2];
    const float* W1   = (const float*)d_in[3];
    const float* b1   = (const float*)d_in[4];
    const float* W2   = (const float*)d_in[5];
    const float* b2   = (const float*)d_in[6];
    const float* W3   = (const float*)d_in[7];
    const float* b3   = (const float*)d_in[8];
    const float* Wlin = (const float*)d_in[9];
    const float* blin = (const float*)d_in[10];
    float* out = (float*)d_out;

    const int* src = ei;
    const int* dst = ei + N_EDGES;

    float* ws = (float*)d_ws;
    float* ew     = ws;                                  // E
    float* dinv   = ew + N_EDGES;                        // N
    float* dinv3  = dinv + N_NODES;                      // N
    float* logits = dinv3 + N_NODES;                     // N*8
    int* cnt       = (int*)(logits + (size_t)N_NODES * 8);
    int* cur       = cnt + N_NODES;
    int* row_start = cur + N_NODES;                      // N+1
    int* bsum      = row_start + N_NODES + 1;            // SCAN_BLOCKS
    uint2* ep  = (uint2*)(((uintptr_t)(bsum + SCAN_BLOCKS) + 127) & ~(uintptr_t)127);  // E
    uint2* ep3 = ep + N_EDGES;                           // E
    u16* hb  = (u16*)(ep3 + N_EDGES);                    // M_PAD*256
    u16* x1b = hb  + (size_t)M_PAD * 256;
    u16* x2b = x1b + (size_t)M_PAD * 256;
    u16* x3b = x2b + (size_t)M_PAD * 256;
    u16* wt1 = x3b + (size_t)M_PAD * 256;                // 256*512
    u16* wt2 = wt1 + 256 * 512;
    u16* wt3 = wt2 + 256 * 256;

    dim3 blk(256);
    dim3 blk64(64);
    int nodeBlocks  = (N_NODES + 255) / 256;
    int edgeBlocks  = (N_EDGES + 255) / 256;
    int gathBlocks  = (N_NODES + 3) / 4;
    int rowBlocks32 = (N_NODES + 31) / 32;
    dim3 gemmGrid(4, M_PAD / 32);    // x = col-block (fastest): 4 col blocks of a row
                                     // panel run together -> A fetched once, L2-shared

    // prep + CSR
    init_k<<<nodeBlocks, blk, 0, stream>>>(dinv, cnt, cur);
    edge_deg_k<<<edgeBlocks, blk, 0, stream>>>(ewp, dst, dinv, cnt, ew);
    finalize_dinv_k<<<nodeBlocks, blk, 0, stream>>>(dinv, cnt, dinv3);
    scan1_k<<<SCAN_BLOCKS, blk, 0, stream>>>(cnt, row_start, bsum);
    scan2_k<<<1, blk, 0, stream>>>(bsum);
    scan3_k<<<SCAN_BLOCKS, blk, 0, stream>>>(row_start, bsum);
    fill_k<<<edgeBlocks, blk, 0, stream>>>(src, dst, ew, dinv, dinv3, row_start, cur, ep, ep3);

    // weights + pads
    wtrans_all_k<<<(256 * 512 + 2 * 256 * 256 + 255) / 256, blk, 0, stream>>>(
        W1, W2, W3, wt1, wt2, wt3);
    zeropad_k<<<48, blk, 0, stream>>>(x1b, x2b);

    // ---- layer 1 (A = fp32 x, converted in registers)
    gemm_rr_k<true, 3><<<gemmGrid, blk64, 0, stream>>>(x, wt1, hb, NFEAT);
    gather_k<true><<<gathBlocks, blk, 0, stream>>>(hb, row_start, ep, dinv, b1, x1b);
    logits_acc_k<true><<<rowBlocks32, blk, 0, stream>>>(x1b, Wlin, blin, logits, 0);

    // ---- layer 2
    gemm_rr_k<false, 4><<<gemmGrid, blk64, 0, stream>>>(x1b, wt2, hb, NHID);
    gather_k<true><<<gathBlocks, blk, 0, stream>>>(hb, row_start, ep, dinv, b2, x2b);
    logits_acc_k<false><<<rowBlocks32, blk, 0, stream>>>(x2b, Wlin, blin, logits, 1);

    // ---- layer 3 (ones edge weights)
    gemm_rr_k<false, 4><<<gemmGrid, blk64, 0, stream>>>(x2b, wt3, hb, NHID);
    gather_k<false><<<gathBlocks, blk, 0, stream>>>(hb, row_start, ep3, dinv3, b3, x3b);
    logits_acc_k<false><<<rowBlocks32, blk, 0, stream>>>(x3b, Wlin, blin, logits, 2);

    // ---- output
    log_softmax_k<<<nodeBlocks, blk, 0, stream>>>(logits, out);
}

// Round 10
// 324.559 us; speedup vs baseline: 1.2623x; 1.2623x over previous
//
#include <hip/hip_runtime.h>
#include <math.h>

#define N_NODES 50000
#define N_EDGES 400000
#define M_PAD 50048
#define NFEAT 512
#define NHID 256
#define NCLASS 8
#define SCAN_BLOCKS ((N_NODES + 255) / 256)   // 196

typedef unsigned short u16;
typedef __attribute__((ext_vector_type(8))) unsigned short u16x8;
typedef __attribute__((ext_vector_type(8))) short s16x8;
typedef __attribute__((ext_vector_type(4))) float f32x4;

__device__ __forceinline__ float bf2f(u16 u) {
    union { unsigned int i; float f; } v; v.i = ((unsigned int)u) << 16; return v.f;
}
__device__ __forceinline__ float bf2f_hi(unsigned int packed) {
    union { unsigned int i; float f; } v; v.i = packed & 0xffff0000u; return v.f;
}
__device__ __forceinline__ float bf2f_lo(unsigned int packed) {
    union { unsigned int i; float f; } v; v.i = packed << 16; return v.f;
}
__device__ __forceinline__ u16 f2bf(float f) {
    union { float f; unsigned int i; } v; v.f = f;
    unsigned int r = v.i + 0x7fffu + ((v.i >> 16) & 1u);
    return (u16)(r >> 16);
}

// ---------------- prep: degrees, CSR ----------------

__global__ void init_k(float* deg, int* cnt, int* cur) {
    int i = blockIdx.x * blockDim.x + threadIdx.x;
    if (i < N_NODES) { deg[i] = 1.0f; cnt[i] = 0; cur[i] = 0; }
}

__global__ void edge_deg_k(const float* __restrict__ p, const int* __restrict__ dst,
                           float* __restrict__ deg, int* __restrict__ cnt,
                           float* __restrict__ ew_out) {
    int e = blockIdx.x * blockDim.x + threadIdx.x;
    if (e >= N_EDGES) return;
    float ew = 1.0f / (1.0f + expf(-p[e]));
    ew_out[e] = ew;
    int d = dst[e];
    atomicAdd(&deg[d], ew);
    atomicAdd(&cnt[d], 1);
}

__global__ void finalize_dinv_k(float* __restrict__ deg, const int* __restrict__ cnt,
                                float* __restrict__ dinv3) {
    int i = blockIdx.x * blockDim.x + threadIdx.x;
    if (i < N_NODES) {
        deg[i]   = 1.0f / sqrtf(deg[i]);
        dinv3[i] = 1.0f / sqrtf(1.0f + (float)cnt[i]);
    }
}

__global__ __launch_bounds__(256) void scan1_k(const int* __restrict__ cnt,
                                               int* __restrict__ row_start,
                                               int* __restrict__ bsum) {
    __shared__ int tmp[256];
    int t = threadIdx.x;
    int g = blockIdx.x * 256 + t;
    int v = (g < N_NODES) ? cnt[g] : 0;
    tmp[t] = v;
    __syncthreads();
    #pragma unroll
    for (int off = 1; off < 256; off <<= 1) {
        int u = (t >= off) ? tmp[t - off] : 0;
        __syncthreads();
        tmp[t] += u;
        __syncthreads();
    }
    if (g < N_NODES) row_start[g] = tmp[t] - v;
    if (t == 255) bsum[blockIdx.x] = tmp[255];
}

__global__ __launch_bounds__(256) void scan2_k(int* __restrict__ bsum) {
    __shared__ int tmp[256];
    int t = threadIdx.x;
    int v = (t < SCAN_BLOCKS) ? bsum[t] : 0;
    tmp[t] = v;
    __syncthreads();
    #pragma unroll
    for (int off = 1; off < 256; off <<= 1) {
        int u = (t >= off) ? tmp[t - off] : 0;
        __syncthreads();
        tmp[t] += u;
        __syncthreads();
    }
    if (t < SCAN_BLOCKS) bsum[t] = tmp[t] - v;
}

__global__ __launch_bounds__(256) void scan3_k(int* __restrict__ row_start,
                                               const int* __restrict__ bsum) {
    int t = threadIdx.x;
    int g = blockIdx.x * 256 + t;
    if (g < N_NODES) row_start[g] += bsum[blockIdx.x];
    if (g == 0) row_start[N_NODES] = N_EDGES;
}

__global__ void fill_k(const int* __restrict__ src, const int* __restrict__ dst,
                       const float* __restrict__ ew, const float* __restrict__ dinv,
                       const float* __restrict__ dinv3,
                       const int* __restrict__ row_start, int* __restrict__ cur,
                       uint2* __restrict__ ep, uint2* __restrict__ ep3) {
    int e = blockIdx.x * blockDim.x + threadIdx.x;
    if (e >= N_EDGES) return;
    int s = src[e], d = dst[e];
    float w  = dinv[s] * ew[e] * dinv[d];
    float w3 = dinv3[s] * dinv3[d];
    int p = atomicAdd(&cur[d], 1);
    int slot = row_start[d] + p;
    ep[slot]  = make_uint2((unsigned int)s, __float_as_uint(w));
    ep3[slot] = make_uint2((unsigned int)s, __float_as_uint(w3));
}

// ---------------- weight transpose: W fp32 [K][256] -> Wt bf16 [256][K] ----------------

__global__ void wtrans_all_k(const float* __restrict__ W1, const float* __restrict__ W2,
                             const float* __restrict__ W3, u16* __restrict__ wt1,
                             u16* __restrict__ wt2, u16* __restrict__ wt3) {
    int idx = blockIdx.x * 256 + threadIdx.x;
    const float* W; u16* Wt; int K;
    if (idx < 256 * 512)           { W = W1; Wt = wt1; K = 512; }
    else if (idx < 256 * 512 + 256 * 256) { idx -= 256 * 512; W = W2; Wt = wt2; K = 256; }
    else if (idx < 256 * 512 + 2 * 256 * 256) { idx -= 256 * 512 + 256 * 256; W = W3; Wt = wt3; K = 256; }
    else return;
    int n = idx / K, k = idx - n * K;
    Wt[(size_t)n * K + k] = f2bf(W[(size_t)k * 256 + n]);
}

__global__ void zeropad_k(u16* a, u16* b) {
    int i = blockIdx.x * 256 + threadIdx.x;
    if (i < (M_PAD - N_NODES) * 256) {
        a[(size_t)N_NODES * 256 + i] = 0;
        b[(size_t)N_NODES * 256 + i] = 0;
    }
}

// ---------------- bf16 MFMA GEMM (r6 structure + single-barrier dbuf) ----------------
// C[M_PAD x 256] = A[M_PAD x K] @ BT[256 x K]^T. 128x128 tile, BK=32, 4 waves.
// LDS double-buffered: ONE barrier per K-step (iter t reads buf[t&1], writes t+1
// into buf[t&1 ^ 1]; barrier at end fences both the new writes and the old reads).

__device__ __forceinline__ u16x8 ldcvt_f32(const float* p, bool ok) {
    u16x8 o = {0, 0, 0, 0, 0, 0, 0, 0};
    if (ok) {
        float4 a = *(const float4*)p;
        float4 b = *(const float4*)(p + 4);
        o[0] = f2bf(a.x); o[1] = f2bf(a.y); o[2] = f2bf(a.z); o[3] = f2bf(a.w);
        o[4] = f2bf(b.x); o[5] = f2bf(b.y); o[6] = f2bf(b.z); o[7] = f2bf(b.w);
    }
    return o;
}

template <bool AF32>
__global__ __launch_bounds__(256) void gemm_bf16_k(const void* __restrict__ Ap,
                                                   const u16* __restrict__ BT,
                                                   u16* __restrict__ C, int K) {
    __shared__ u16 Asl[2][128 * 40];   // padded stride 40: ~2-way (free) bank phases
    __shared__ u16 Bsl[2][128 * 40];
    int tid = threadIdx.x;
    int lane = tid & 63;
    int wid = tid >> 6;
    int wm = wid >> 1, wn = wid & 1;
    int row0 = blockIdx.x * 128;
    int col0 = blockIdx.y * 128;

    int c0 = tid, c1 = tid + 256;
    int ar0 = c0 >> 2, ak0 = (c0 & 3) << 3;
    int ar1 = c1 >> 2, ak1 = (c1 & 3) << 3;
    const u16*   A16 = (const u16*)Ap;
    const float* A32 = (const float*)Ap;
    bool ok0 = (row0 + ar0) < N_NODES;
    bool ok1 = (row0 + ar1) < N_NODES;
    const u16* Ag0 = A16 + (size_t)(row0 + ar0) * K + ak0;
    const u16* Ag1 = A16 + (size_t)(row0 + ar1) * K + ak1;
    const float* Af0 = A32 + (size_t)(row0 + ar0) * K + ak0;
    const float* Af1 = A32 + (size_t)(row0 + ar1) * K + ak1;
    const u16* Bg0 = BT + (size_t)(col0 + ar0) * K + ak0;
    const u16* Bg1 = BT + (size_t)(col0 + ar1) * K + ak1;
    int la0 = ar0 * 40 + ak0, la1 = ar1 * 40 + ak1;

    u16x8 ra0, ra1, rb0, rb1;
    if (AF32) { ra0 = ldcvt_f32(Af0, ok0); ra1 = ldcvt_f32(Af1, ok1); }
    else      { ra0 = *(const u16x8*)Ag0;  ra1 = *(const u16x8*)Ag1; }
    rb0 = *(const u16x8*)Bg0;
    rb1 = *(const u16x8*)Bg1;
    *(u16x8*)&Asl[0][la0] = ra0; *(u16x8*)&Asl[0][la1] = ra1;
    *(u16x8*)&Bsl[0][la0] = rb0; *(u16x8*)&Bsl[0][la1] = rb1;
    __syncthreads();

    f32x4 acc[4][4] = {};
    int arow = wm * 64 + (lane & 15);
    int bcol = wn * 64 + (lane & 15);
    int kg = (lane >> 4) << 3;

    int nt = K >> 5;
    for (int t = 0; t < nt; ++t) {
        int cur = t & 1;
        if (t + 1 < nt) {                      // issue next tile's loads early
            int ko = (t + 1) << 5;
            if (AF32) { ra0 = ldcvt_f32(Af0 + ko, ok0); ra1 = ldcvt_f32(Af1 + ko, ok1); }
            else      { ra0 = *(const u16x8*)(Ag0 + ko); ra1 = *(const u16x8*)(Ag1 + ko); }
            rb0 = *(const u16x8*)(Bg0 + ko);
            rb1 = *(const u16x8*)(Bg1 + ko);
        }
        s16x8 af[4], bf[4];
        #pragma unroll
        for (int m = 0; m < 4; ++m)
            af[m] = *(const s16x8*)&Asl[cur][(arow + m * 16) * 40 + kg];
        #pragma unroll
        for (int n = 0; n < 4; ++n)
            bf[n] = *(const s16x8*)&Bsl[cur][(bcol + n * 16) * 40 + kg];
        #pragma unroll
        for (int m = 0; m < 4; ++m)
            #pragma unroll
            for (int n = 0; n < 4; ++n)
                acc[m][n] = __builtin_amdgcn_mfma_f32_16x16x32_bf16(af[m], bf[n], acc[m][n], 0, 0, 0);
        if (t + 1 < nt) {
            *(u16x8*)&Asl[cur ^ 1][la0] = ra0; *(u16x8*)&Asl[cur ^ 1][la1] = ra1;
            *(u16x8*)&Bsl[cur ^ 1][la0] = rb0; *(u16x8*)&Bsl[cur ^ 1][la1] = rb1;
            __syncthreads();                   // single barrier per K-step
        }
    }

    // C/D layout: col = lane&15, row = (lane>>4)*4 + r
    int crow0 = row0 + wm * 64 + ((lane >> 4) << 2);
    int ccol  = col0 + wn * 64 + (lane & 15);
    #pragma unroll
    for (int m = 0; m < 4; ++m)
        #pragma unroll
        for (int n = 0; n < 4; ++n)
            #pragma unroll
            for (int r = 0; r < 4; ++r)
                C[(size_t)(crow0 + m * 16 + r) * 256 + ccol + n * 16] = f2bf(acc[m][n][r]);
}

// ---------------- gather (bf16 in/out), half-wave per edge ----------------
// One wave per node. Lane owns 16B (8 bf16) of the 256-dim row (c = lane&31).
// Lanes 0-31 process even-indexed edges, 32-63 odd-indexed; x2 unroll each
// (4 rows in flight); __shfl_xor(32) combines the two half-sums.

__device__ __forceinline__ void fma8(float* acc, uint4 u, float w) {
    acc[0] += bf2f_lo(u.x) * w; acc[1] += bf2f_hi(u.x) * w;
    acc[2] += bf2f_lo(u.y) * w; acc[3] += bf2f_hi(u.y) * w;
    acc[4] += bf2f_lo(u.z) * w; acc[5] += bf2f_hi(u.z) * w;
    acc[6] += bf2f_lo(u.w) * w; acc[7] += bf2f_hi(u.w) * w;
}

template <bool RELU>
__global__ __launch_bounds__(256) void gather_k(const u16* __restrict__ h,
                                                const int* __restrict__ row_start,
                                                const uint2* __restrict__ ep,
                                                const float* __restrict__ dinv,
                                                const float* __restrict__ bias,
                                                u16* __restrict__ outb) {
    int node = blockIdx.x * 4 + (threadIdx.x >> 6);
    if (node >= N_NODES) return;
    int lane = threadIdx.x & 63;
    int half = lane >> 5;
    int c = lane & 31;                       // 16B chunk index within row

    float di = dinv[node];
    float sw = di * di;
    uint4 hv = *(const uint4*)(h + (size_t)node * 256 + c * 8);
    float acc[8];
    if (half == 0) {
        acc[0] = bf2f_lo(hv.x) * sw; acc[1] = bf2f_hi(hv.x) * sw;
        acc[2] = bf2f_lo(hv.y) * sw; acc[3] = bf2f_hi(hv.y) * sw;
        acc[4] = bf2f_lo(hv.z) * sw; acc[5] = bf2f_hi(hv.z) * sw;
        acc[6] = bf2f_lo(hv.w) * sw; acc[7] = bf2f_hi(hv.w) * sw;
    } else {
        #pragma unroll
        for (int i = 0; i < 8; ++i) acc[i] = 0.f;
    }

    int beg = row_start[node], end = row_start[node + 1];
    int jh = beg + half;                     // this half's edge stream (stride 2)
    for (; jh + 2 < end; jh += 4) {          // 2 edges per half in flight
        uint2 e0 = ep[jh], e1 = ep[jh + 2];
        uint4 u0 = *(const uint4*)(h + (size_t)e0.x * 256 + c * 8);
        uint4 u1 = *(const uint4*)(h + (size_t)e1.x * 256 + c * 8);
        fma8(acc, u0, __uint_as_float(e0.y));
        fma8(acc, u1, __uint_as_float(e1.y));
    }
    for (; jh < end; jh += 2) {
        uint2 e = ep[jh];
        uint4 u = *(const uint4*)(h + (size_t)e.x * 256 + c * 8);
        fma8(acc, u, __uint_as_float(e.y));
    }

    #pragma unroll
    for (int i = 0; i < 8; ++i) acc[i] += __shfl_xor(acc[i], 32);

    if (half == 0) {
        float4 bv0 = *(const float4*)&bias[c * 8];
        float4 bv1 = *(const float4*)&bias[c * 8 + 4];
        acc[0] += bv0.x; acc[1] += bv0.y; acc[2] += bv0.z; acc[3] += bv0.w;
        acc[4] += bv1.x; acc[5] += bv1.y; acc[6] += bv1.z; acc[7] += bv1.w;
        if (RELU) {
            #pragma unroll
            for (int i = 0; i < 8; ++i) acc[i] = fmaxf(acc[i], 0.f);
        }
        uint4 o;
        o.x = (unsigned int)f2bf(acc[0]) | ((unsigned int)f2bf(acc[1]) << 16);
        o.y = (unsigned int)f2bf(acc[2]) | ((unsigned int)f2bf(acc[3]) << 16);
        o.z = (unsigned int)f2bf(acc[4]) | ((unsigned int)f2bf(acc[5]) << 16);
        o.w = (unsigned int)f2bf(acc[6]) | ((unsigned int)f2bf(acc[7]) << 16);
        *(uint4*)(outb + (size_t)node * 256 + c * 8) = o;
    }
}

// ---------------- final linear + log_softmax ----------------

template <bool FIRST>
__global__ __launch_bounds__(256) void logits_acc_k(const u16* __restrict__ x,
                                                    const float* __restrict__ Wlin,
                                                    const float* __restrict__ blin,
                                                    float* __restrict__ logits, int seg) {
    __shared__ float Ws[256 * 8];
    int tid = threadIdx.x;
    const float* Wseg = Wlin + (size_t)seg * 256 * 8;
    for (int i = tid; i < 2048; i += 256) Ws[i] = Wseg[i];
    __syncthreads();
    int row = blockIdx.x * 32 + (tid >> 3);
    int c = tid & 7;
    if (row >= N_NODES) return;
    const u16* xr = x + (size_t)row * 256;
    float acc = 0.f;
    for (int k8 = 0; k8 < 32; ++k8) {
        u16x8 v = *(const u16x8*)&xr[k8 * 8];
        #pragma unroll
        for (int i = 0; i < 8; ++i) acc += bf2f(v[i]) * Ws[(k8 * 8 + i) * 8 + c];
    }
    float* lp = &logits[(size_t)row * 8 + c];
    if (FIRST) *lp = acc + blin[c];
    else       *lp += acc;
}

__global__ void log_softmax_k(const float* __restrict__ logits, float* __restrict__ out) {
    int row = blockIdx.x * blockDim.x + threadIdx.x;
    if (row >= N_NODES) return;
    float4 a = *(const float4*)&logits[(size_t)row * 8];
    float4 b = *(const float4*)&logits[(size_t)row * 8 + 4];
    float m = fmaxf(fmaxf(fmaxf(a.x, a.y), fmaxf(a.z, a.w)),
                    fmaxf(fmaxf(b.x, b.y), fmaxf(b.z, b.w)));
    float s = expf(a.x - m) + expf(a.y - m) + expf(a.z - m) + expf(a.w - m)
            + expf(b.x - m) + expf(b.y - m) + expf(b.z - m) + expf(b.w - m);
    float ls = logf(s) + m;
    float* o = &out[(size_t)row * 8];
    o[0] = a.x - ls; o[1] = a.y - ls; o[2] = a.z - ls; o[3] = a.w - ls;
    o[4] = b.x - ls; o[5] = b.y - ls; o[6] = b.z - ls; o[7] = b.w - ls;
}

// ---------------- driver ----------------

extern "C" void kernel_launch(void* const* d_in, const int* in_sizes, int n_in,
                              void* d_out, int out_size, void* d_ws, size_t ws_size,
                              hipStream_t stream) {
    const float* x    = (const float*)d_in[0];
    const int*   ei   = (const int*)d_in[1];
    const float* ewp  = (const float*)d_in[2];
    const float* W1   = (const float*)d_in[3];
    const float* b1   = (const float*)d_in[4];
    const float* W2   = (const float*)d_in[5];
    const float* b2   = (const float*)d_in[6];
    const float* W3   = (const float*)d_in[7];
    const float* b3   = (const float*)d_in[8];
    const float* Wlin = (const float*)d_in[9];
    const float* blin = (const float*)d_in[10];
    float* out = (float*)d_out;

    const int* src = ei;
    const int* dst = ei + N_EDGES;

    float* ws = (float*)d_ws;
    float* ew     = ws;                                  // E
    float* dinv   = ew + N_EDGES;                        // N
    float* dinv3  = dinv + N_NODES;                      // N
    float* logits = dinv3 + N_NODES;                     // N*8
    int* cnt       = (int*)(logits + (size_t)N_NODES * 8);
    int* cur       = cnt + N_NODES;
    int* row_start = cur + N_NODES;                      // N+1
    int* bsum      = row_start + N_NODES + 1;            // SCAN_BLOCKS
    uint2* ep  = (uint2*)(((uintptr_t)(bsum + SCAN_BLOCKS) + 127) & ~(uintptr_t)127);  // E
    uint2* ep3 = ep + N_EDGES;                           // E
    u16* hb  = (u16*)(ep3 + N_EDGES);                    // M_PAD*256
    u16* x1b = hb  + (size_t)M_PAD * 256;
    u16* x2b = x1b + (size_t)M_PAD * 256;
    u16* x3b = x2b + (size_t)M_PAD * 256;
    u16* wt1 = x3b + (size_t)M_PAD * 256;                // 256*512
    u16* wt2 = wt1 + 256 * 512;
    u16* wt3 = wt2 + 256 * 256;

    dim3 blk(256);
    int nodeBlocks  = (N_NODES + 255) / 256;
    int edgeBlocks  = (N_EDGES + 255) / 256;
    int gathBlocks  = (N_NODES + 3) / 4;
    int rowBlocks32 = (N_NODES + 31) / 32;
    dim3 gemmGrid(M_PAD / 128, 2);

    // prep + CSR
    init_k<<<nodeBlocks, blk, 0, stream>>>(dinv, cnt, cur);
    edge_deg_k<<<edgeBlocks, blk, 0, stream>>>(ewp, dst, dinv, cnt, ew);
    finalize_dinv_k<<<nodeBlocks, blk, 0, stream>>>(dinv, cnt, dinv3);
    scan1_k<<<SCAN_BLOCKS, blk, 0, stream>>>(cnt, row_start, bsum);
    scan2_k<<<1, blk, 0, stream>>>(bsum);
    scan3_k<<<SCAN_BLOCKS, blk, 0, stream>>>(row_start, bsum);
    fill_k<<<edgeBlocks, blk, 0, stream>>>(src, dst, ew, dinv, dinv3, row_start, cur, ep, ep3);

    // weights + pads
    wtrans_all_k<<<(256 * 512 + 2 * 256 * 256 + 255) / 256, blk, 0, stream>>>(
        W1, W2, W3, wt1, wt2, wt3);
    zeropad_k<<<48, blk, 0, stream>>>(x1b, x2b);

    // ---- layer 1 (A = fp32 x, converted in registers)
    gemm_bf16_k<true><<<gemmGrid, blk, 0, stream>>>(x, wt1, hb, NFEAT);
    gather_k<true><<<gathBlocks, blk, 0, stream>>>(hb, row_start, ep, dinv, b1, x1b);
    logits_acc_k<true><<<rowBlocks32, blk, 0, stream>>>(x1b, Wlin, blin, logits, 0);

    // ---- layer 2
    gemm_bf16_k<false><<<gemmGrid, blk, 0, stream>>>(x1b, wt2, hb, NHID);
    gather_k<true><<<gathBlocks, blk, 0, stream>>>(hb, row_start, ep, dinv, b2, x2b);
    logits_acc_k<false><<<rowBlocks32, blk, 0, stream>>>(x2b, Wlin, blin, logits, 1);

    // ---- layer 3 (ones edge weights)
    gemm_bf16_k<false><<<gemmGrid, blk, 0, stream>>>(x2b, wt3, hb, NHID);
    gather_k<false><<<gathBlocks, blk, 0, stream>>>(hb, row_start, ep3, dinv3, b3, x3b);
    logits_acc_k<false><<<rowBlocks32, blk, 0, stream>>>(x3b, Wlin, blin, logits, 2);

    // ---- output
    log_softmax_k<<<nodeBlocks, blk, 0, stream>>>(logits, out);
}

// Round 11
// 311.755 us; speedup vs baseline: 1.3142x; 1.0411x over previous
//
#include <hip/hip_runtime.h>
#include <math.h>

#define N_NODES 50000
#define N_EDGES 400000
#define M_PAD 50048
#define NFEAT 512
#define NHID 256
#define NCLASS 8
#define SCAN_BLOCKS ((N_NODES + 255) / 256)   // 196

typedef unsigned short u16;
typedef __attribute__((ext_vector_type(8))) unsigned short u16x8;
typedef __attribute__((ext_vector_type(8))) short s16x8;
typedef __attribute__((ext_vector_type(4))) float f32x4;

__device__ __forceinline__ float bf2f(u16 u) {
    union { unsigned int i; float f; } v; v.i = ((unsigned int)u) << 16; return v.f;
}
__device__ __forceinline__ float bf2f_hi(unsigned int packed) {
    union { unsigned int i; float f; } v; v.i = packed & 0xffff0000u; return v.f;
}
__device__ __forceinline__ float bf2f_lo(unsigned int packed) {
    union { unsigned int i; float f; } v; v.i = packed << 16; return v.f;
}
__device__ __forceinline__ u16 f2bf(float f) {
    union { float f; unsigned int i; } v; v.f = f;
    unsigned int r = v.i + 0x7fffu + ((v.i >> 16) & 1u);
    return (u16)(r >> 16);
}

// ---------------- prep: degrees, CSR ----------------

__global__ void init_k(float* deg, int* cnt, int* cur) {
    int i = blockIdx.x * blockDim.x + threadIdx.x;
    if (i < N_NODES) { deg[i] = 1.0f; cnt[i] = 0; cur[i] = 0; }
}

__global__ void edge_deg_k(const float* __restrict__ p, const int* __restrict__ dst,
                           float* __restrict__ deg, int* __restrict__ cnt,
                           float* __restrict__ ew_out) {
    int e = blockIdx.x * blockDim.x + threadIdx.x;
    if (e >= N_EDGES) return;
    float ew = 1.0f / (1.0f + expf(-p[e]));
    ew_out[e] = ew;
    int d = dst[e];
    atomicAdd(&deg[d], ew);
    atomicAdd(&cnt[d], 1);
}

__global__ void finalize_dinv_k(float* __restrict__ deg, const int* __restrict__ cnt,
                                float* __restrict__ dinv3) {
    int i = blockIdx.x * blockDim.x + threadIdx.x;
    if (i < N_NODES) {
        deg[i]   = 1.0f / sqrtf(deg[i]);
        dinv3[i] = 1.0f / sqrtf(1.0f + (float)cnt[i]);
    }
}

// scan1: per-256-block exclusive scan; bsum[b] = block total.
// row_start stays block-local; consumers add bsum[idx>>8] (scan3 eliminated).
__global__ __launch_bounds__(256) void scan1_k(const int* __restrict__ cnt,
                                               int* __restrict__ row_start,
                                               int* __restrict__ bsum) {
    __shared__ int tmp[256];
    int t = threadIdx.x;
    int g = blockIdx.x * 256 + t;
    int v = (g < N_NODES) ? cnt[g] : 0;
    tmp[t] = v;
    __syncthreads();
    #pragma unroll
    for (int off = 1; off < 256; off <<= 1) {
        int u = (t >= off) ? tmp[t - off] : 0;
        __syncthreads();
        tmp[t] += u;
        __syncthreads();
    }
    if (g < N_NODES) row_start[g] = tmp[t] - v;
    if (t == 255) bsum[blockIdx.x] = tmp[255];
}

// scan2: exclusive scan of bsum in place; also writes row_start[N_NODES] = last
// block's local total so that end(node N-1) = row_start[N] + bsum[195] = E.
__global__ __launch_bounds__(256) void scan2_k(int* __restrict__ bsum,
                                               int* __restrict__ row_start) {
    __shared__ int tmp[256];
    int t = threadIdx.x;
    int v = (t < SCAN_BLOCKS) ? bsum[t] : 0;
    tmp[t] = v;
    __syncthreads();
    #pragma unroll
    for (int off = 1; off < 256; off <<= 1) {
        int u = (t >= off) ? tmp[t - off] : 0;
        __syncthreads();
        tmp[t] += u;
        __syncthreads();
    }
    if (t < SCAN_BLOCKS) bsum[t] = tmp[t] - v;
    if (t == SCAN_BLOCKS - 1) row_start[N_NODES] = v;   // local total of last block
}

__global__ void fill_k(const int* __restrict__ src, const int* __restrict__ dst,
                       const float* __restrict__ ew, const float* __restrict__ dinv,
                       const float* __restrict__ dinv3,
                       const int* __restrict__ row_start, const int* __restrict__ bsum,
                       int* __restrict__ cur,
                       uint2* __restrict__ ep, uint2* __restrict__ ep3) {
    int e = blockIdx.x * blockDim.x + threadIdx.x;
    if (e >= N_EDGES) return;
    int s = src[e], d = dst[e];
    float w  = dinv[s] * ew[e] * dinv[d];
    float w3 = dinv3[s] * dinv3[d];
    int p = atomicAdd(&cur[d], 1);
    int slot = row_start[d] + bsum[d >> 8] + p;
    ep[slot]  = make_uint2((unsigned int)s, __float_as_uint(w));
    ep3[slot] = make_uint2((unsigned int)s, __float_as_uint(w3));
}

// ---------------- weight transpose + zeropad (merged) ----------------
// W fp32 [K][256] -> Wt bf16 [256][K]; tail region zeroes pad rows of x1b/x2b.

#define WT_TOTAL (256 * 512 + 2 * 256 * 256)
#define ZP_TOTAL ((M_PAD - N_NODES) * 256)

__global__ void wtrans_zp_k(const float* __restrict__ W1, const float* __restrict__ W2,
                            const float* __restrict__ W3, u16* __restrict__ wt1,
                            u16* __restrict__ wt2, u16* __restrict__ wt3,
                            u16* __restrict__ zp_a, u16* __restrict__ zp_b) {
    int idx = blockIdx.x * 256 + threadIdx.x;
    if (idx < WT_TOTAL) {
        const float* W; u16* Wt; int K;
        if (idx < 256 * 512)                  { W = W1; Wt = wt1; K = 512; }
        else if (idx < 256 * 512 + 256 * 256) { idx -= 256 * 512; W = W2; Wt = wt2; K = 256; }
        else                                  { idx -= 256 * 512 + 256 * 256; W = W3; Wt = wt3; K = 256; }
        int n = idx / K, k = idx - n * K;
        Wt[(size_t)n * K + k] = f2bf(W[(size_t)k * 256 + n]);
        return;
    }
    int z = idx - WT_TOTAL;
    if (z < ZP_TOTAL) {
        zp_a[(size_t)N_NODES * 256 + z] = 0;
        zp_b[(size_t)N_NODES * 256 + z] = 0;
    }
}

// ---------------- bf16 MFMA GEMM (r6 structure — measured best) ----------------
// C[M_PAD x 256] = A[M_PAD x K] @ BT[256 x K]^T. 128x128 tile, BK=32, 4 waves,
// padded-40 LDS rows (~2-way bank phases, free), register prefetch of next tile.
// AF32: layer-1 A is fp32, converted in registers (pad rows read as 0).

__device__ __forceinline__ u16x8 ldcvt_f32(const float* p, bool ok) {
    u16x8 o = {0, 0, 0, 0, 0, 0, 0, 0};
    if (ok) {
        float4 a = *(const float4*)p;
        float4 b = *(const float4*)(p + 4);
        o[0] = f2bf(a.x); o[1] = f2bf(a.y); o[2] = f2bf(a.z); o[3] = f2bf(a.w);
        o[4] = f2bf(b.x); o[5] = f2bf(b.y); o[6] = f2bf(b.z); o[7] = f2bf(b.w);
    }
    return o;
}

template <bool AF32>
__global__ __launch_bounds__(256) void gemm_bf16_k(const void* __restrict__ Ap,
                                                   const u16* __restrict__ BT,
                                                   u16* __restrict__ C, int K) {
    __shared__ u16 Asl[128 * 40];
    __shared__ u16 Bsl[128 * 40];
    int tid = threadIdx.x;
    int lane = tid & 63;
    int wid = tid >> 6;
    int wm = wid >> 1, wn = wid & 1;
    int row0 = blockIdx.x * 128;
    int col0 = blockIdx.y * 128;

    int c0 = tid, c1 = tid + 256;
    int ar0 = c0 >> 2, ak0 = (c0 & 3) << 3;
    int ar1 = c1 >> 2, ak1 = (c1 & 3) << 3;
    const u16*   A16 = (const u16*)Ap;
    const float* A32 = (const float*)Ap;
    bool ok0 = (row0 + ar0) < N_NODES;
    bool ok1 = (row0 + ar1) < N_NODES;
    const u16* Ag0 = A16 + (size_t)(row0 + ar0) * K + ak0;
    const u16* Ag1 = A16 + (size_t)(row0 + ar1) * K + ak1;
    const float* Af0 = A32 + (size_t)(row0 + ar0) * K + ak0;
    const float* Af1 = A32 + (size_t)(row0 + ar1) * K + ak1;
    const u16* Bg0 = BT + (size_t)(col0 + ar0) * K + ak0;
    const u16* Bg1 = BT + (size_t)(col0 + ar1) * K + ak1;
    int la0 = ar0 * 40 + ak0, la1 = ar1 * 40 + ak1;

    u16x8 ra0, ra1, rb0, rb1;
    if (AF32) { ra0 = ldcvt_f32(Af0, ok0); ra1 = ldcvt_f32(Af1, ok1); }
    else      { ra0 = *(const u16x8*)Ag0;  ra1 = *(const u16x8*)Ag1; }
    rb0 = *(const u16x8*)Bg0;
    rb1 = *(const u16x8*)Bg1;

    f32x4 acc[4][4] = {};
    int arow = wm * 64 + (lane & 15);
    int bcol = wn * 64 + (lane & 15);
    int kg = (lane >> 4) << 3;

    int nt = K >> 5;
    for (int t = 0; t < nt; ++t) {
        __syncthreads();
        *(u16x8*)&Asl[la0] = ra0; *(u16x8*)&Asl[la1] = ra1;
        *(u16x8*)&Bsl[la0] = rb0; *(u16x8*)&Bsl[la1] = rb1;
        __syncthreads();
        if (t + 1 < nt) {
            int ko = (t + 1) << 5;
            if (AF32) { ra0 = ldcvt_f32(Af0 + ko, ok0); ra1 = ldcvt_f32(Af1 + ko, ok1); }
            else      { ra0 = *(const u16x8*)(Ag0 + ko); ra1 = *(const u16x8*)(Ag1 + ko); }
            rb0 = *(const u16x8*)(Bg0 + ko);
            rb1 = *(const u16x8*)(Bg1 + ko);
        }
        s16x8 af[4], bf[4];
        #pragma unroll
        for (int m = 0; m < 4; ++m)
            af[m] = *(const s16x8*)&Asl[(arow + m * 16) * 40 + kg];
        #pragma unroll
        for (int n = 0; n < 4; ++n)
            bf[n] = *(const s16x8*)&Bsl[(bcol + n * 16) * 40 + kg];
        #pragma unroll
        for (int m = 0; m < 4; ++m)
            #pragma unroll
            for (int n = 0; n < 4; ++n)
                acc[m][n] = __builtin_amdgcn_mfma_f32_16x16x32_bf16(af[m], bf[n], acc[m][n], 0, 0, 0);
    }

    // C/D layout: col = lane&15, row = (lane>>4)*4 + r
    int crow0 = row0 + wm * 64 + ((lane >> 4) << 2);
    int ccol  = col0 + wn * 64 + (lane & 15);
    #pragma unroll
    for (int m = 0; m < 4; ++m)
        #pragma unroll
        for (int n = 0; n < 4; ++n)
            #pragma unroll
            for (int r = 0; r < 4; ++r)
                C[(size_t)(crow0 + m * 16 + r) * 256 + ccol + n * 16] = f2bf(acc[m][n][r]);
}

// ---------------- gather (bf16 in/out), edge loop unrolled x8/x4/x1 ----------------

__device__ __forceinline__ void fma4(float4& acc, uint2 u, float w) {
    acc.x += bf2f_lo(u.x) * w; acc.y += bf2f_hi(u.x) * w;
    acc.z += bf2f_lo(u.y) * w; acc.w += bf2f_hi(u.y) * w;
}

template <bool RELU>
__global__ __launch_bounds__(256) void gather_k(const u16* __restrict__ h,
                                                const int* __restrict__ row_start,
                                                const int* __restrict__ bsum,
                                                const uint2* __restrict__ ep,
                                                const float* __restrict__ dinv,
                                                const float* __restrict__ bias,
                                                u16* __restrict__ outb) {
    int node = blockIdx.x * 4 + (threadIdx.x >> 6);
    if (node >= N_NODES) return;
    int lane = threadIdx.x & 63;

    float di = dinv[node];
    float sw = di * di;
    uint2 hv = *(const uint2*)(h + (size_t)node * 256 + lane * 4);
    float4 acc;
    acc.x = bf2f_lo(hv.x) * sw; acc.y = bf2f_hi(hv.x) * sw;
    acc.z = bf2f_lo(hv.y) * sw; acc.w = bf2f_hi(hv.y) * sw;

    int beg = row_start[node] + bsum[node >> 8];
    int end = row_start[node + 1] + bsum[(node + 1) >> 8];
    int j = beg;
    for (; j + 8 <= end; j += 8) {
        uint2 e0 = ep[j],     e1 = ep[j + 1], e2 = ep[j + 2], e3 = ep[j + 3];
        uint2 e4 = ep[j + 4], e5 = ep[j + 5], e6 = ep[j + 6], e7 = ep[j + 7];
        uint2 u0 = *(const uint2*)(h + (size_t)e0.x * 256 + lane * 4);
        uint2 u1 = *(const uint2*)(h + (size_t)e1.x * 256 + lane * 4);
        uint2 u2 = *(const uint2*)(h + (size_t)e2.x * 256 + lane * 4);
        uint2 u3 = *(const uint2*)(h + (size_t)e3.x * 256 + lane * 4);
        uint2 u4 = *(const uint2*)(h + (size_t)e4.x * 256 + lane * 4);
        uint2 u5 = *(const uint2*)(h + (size_t)e5.x * 256 + lane * 4);
        uint2 u6 = *(const uint2*)(h + (size_t)e6.x * 256 + lane * 4);
        uint2 u7 = *(const uint2*)(h + (size_t)e7.x * 256 + lane * 4);
        fma4(acc, u0, __uint_as_float(e0.y)); fma4(acc, u1, __uint_as_float(e1.y));
        fma4(acc, u2, __uint_as_float(e2.y)); fma4(acc, u3, __uint_as_float(e3.y));
        fma4(acc, u4, __uint_as_float(e4.y)); fma4(acc, u5, __uint_as_float(e5.y));
        fma4(acc, u6, __uint_as_float(e6.y)); fma4(acc, u7, __uint_as_float(e7.y));
    }
    for (; j + 4 <= end; j += 4) {
        uint2 e0 = ep[j], e1 = ep[j + 1], e2 = ep[j + 2], e3 = ep[j + 3];
        uint2 u0 = *(const uint2*)(h + (size_t)e0.x * 256 + lane * 4);
        uint2 u1 = *(const uint2*)(h + (size_t)e1.x * 256 + lane * 4);
        uint2 u2 = *(const uint2*)(h + (size_t)e2.x * 256 + lane * 4);
        uint2 u3 = *(const uint2*)(h + (size_t)e3.x * 256 + lane * 4);
        fma4(acc, u0, __uint_as_float(e0.y)); fma4(acc, u1, __uint_as_float(e1.y));
        fma4(acc, u2, __uint_as_float(e2.y)); fma4(acc, u3, __uint_as_float(e3.y));
    }
    for (; j < end; ++j) {
        uint2 e = ep[j];
        uint2 u = *(const uint2*)(h + (size_t)e.x * 256 + lane * 4);
        fma4(acc, u, __uint_as_float(e.y));
    }
    float4 bv = ((const float4*)bias)[lane];
    acc.x += bv.x; acc.y += bv.y; acc.z += bv.z; acc.w += bv.w;
    if (RELU) {
        acc.x = fmaxf(acc.x, 0.f); acc.y = fmaxf(acc.y, 0.f);
        acc.z = fmaxf(acc.z, 0.f); acc.w = fmaxf(acc.w, 0.f);
    }
    uint2 o;
    o.x = (unsigned int)f2bf(acc.x) | ((unsigned int)f2bf(acc.y) << 16);
    o.y = (unsigned int)f2bf(acc.z) | ((unsigned int)f2bf(acc.w) << 16);
    *(uint2*)(outb + (size_t)node * 256 + lane * 4) = o;
}

// ---------------- final linear (+ fused log_softmax on last segment) ----------------
// MODE 0: logits = dot + blin ; MODE 1: logits += dot ;
// MODE 2: t = logits + dot, out = t - logsumexp(t) via 8-lane shfl reduction.

template <int MODE>
__global__ __launch_bounds__(256) void logits_acc_k(const u16* __restrict__ x,
                                                    const float* __restrict__ Wlin,
                                                    const float* __restrict__ blin,
                                                    float* __restrict__ logits,
                                                    float* __restrict__ out, int seg) {
    __shared__ float Ws[256 * 8];
    int tid = threadIdx.x;
    const float* Wseg = Wlin + (size_t)seg * 256 * 8;
    for (int i = tid; i < 2048; i += 256) Ws[i] = Wseg[i];
    __syncthreads();
    int row = blockIdx.x * 32 + (tid >> 3);
    int c = tid & 7;
    if (row >= N_NODES) return;
    const u16* xr = x + (size_t)row * 256;
    float acc = 0.f;
    for (int k8 = 0; k8 < 32; ++k8) {
        u16x8 v = *(const u16x8*)&xr[k8 * 8];
        #pragma unroll
        for (int i = 0; i < 8; ++i) acc += bf2f(v[i]) * Ws[(k8 * 8 + i) * 8 + c];
    }
    float* lp = &logits[(size_t)row * 8 + c];
    if (MODE == 0) {
        *lp = acc + blin[c];
    } else if (MODE == 1) {
        *lp += acc;
    } else {
        float t = *lp + acc;
        float m = t;
        m = fmaxf(m, __shfl_xor(m, 1));
        m = fmaxf(m, __shfl_xor(m, 2));
        m = fmaxf(m, __shfl_xor(m, 4));
        float s = expf(t - m);
        s += __shfl_xor(s, 1);
        s += __shfl_xor(s, 2);
        s += __shfl_xor(s, 4);
        out[(size_t)row * 8 + c] = t - (logf(s) + m);
    }
}

// ---------------- driver ----------------

extern "C" void kernel_launch(void* const* d_in, const int* in_sizes, int n_in,
                              void* d_out, int out_size, void* d_ws, size_t ws_size,
                              hipStream_t stream) {
    const float* x    = (const float*)d_in[0];
    const int*   ei   = (const int*)d_in[1];
    const float* ewp  = (const float*)d_in[2];
    const float* W1   = (const float*)d_in[3];
    const float* b1   = (const float*)d_in[4];
    const float* W2   = (const float*)d_in[5];
    const float* b2   = (const float*)d_in[6];
    const float* W3   = (const float*)d_in[7];
    const float* b3   = (const float*)d_in[8];
    const float* Wlin = (const float*)d_in[9];
    const float* blin = (const float*)d_in[10];
    float* out = (float*)d_out;

    const int* src = ei;
    const int* dst = ei + N_EDGES;

    float* ws = (float*)d_ws;
    float* ew     = ws;                                  // E
    float* dinv   = ew + N_EDGES;                        // N
    float* dinv3  = dinv + N_NODES;                      // N
    float* logits = dinv3 + N_NODES;                     // N*8
    int* cnt       = (int*)(logits + (size_t)N_NODES * 8);
    int* cur       = cnt + N_NODES;
    int* row_start = cur + N_NODES;                      // N+1 (block-local)
    int* bsum      = row_start + N_NODES + 1;            // SCAN_BLOCKS
    uint2* ep  = (uint2*)(((uintptr_t)(bsum + SCAN_BLOCKS) + 127) & ~(uintptr_t)127);  // E
    uint2* ep3 = ep + N_EDGES;                           // E
    u16* hb  = (u16*)(ep3 + N_EDGES);                    // M_PAD*256
    u16* x1b = hb  + (size_t)M_PAD * 256;
    u16* x2b = x1b + (size_t)M_PAD * 256;
    u16* x3b = x2b + (size_t)M_PAD * 256;
    u16* wt1 = x3b + (size_t)M_PAD * 256;                // 256*512
    u16* wt2 = wt1 + 256 * 512;
    u16* wt3 = wt2 + 256 * 256;

    dim3 blk(256);
    int nodeBlocks  = (N_NODES + 255) / 256;
    int edgeBlocks  = (N_EDGES + 255) / 256;
    int gathBlocks  = (N_NODES + 3) / 4;
    int rowBlocks32 = (N_NODES + 31) / 32;
    dim3 gemmGrid(M_PAD / 128, 2);

    // prep + CSR (scan3 eliminated: consumers add bsum[idx>>8])
    init_k<<<nodeBlocks, blk, 0, stream>>>(dinv, cnt, cur);
    edge_deg_k<<<edgeBlocks, blk, 0, stream>>>(ewp, dst, dinv, cnt, ew);
    finalize_dinv_k<<<nodeBlocks, blk, 0, stream>>>(dinv, cnt, dinv3);
    scan1_k<<<SCAN_BLOCKS, blk, 0, stream>>>(cnt, row_start, bsum);
    scan2_k<<<1, blk, 0, stream>>>(bsum, row_start);
    fill_k<<<edgeBlocks, blk, 0, stream>>>(src, dst, ew, dinv, dinv3, row_start, bsum,
                                           cur, ep, ep3);

    // weights + pads (merged)
    wtrans_zp_k<<<(WT_TOTAL + ZP_TOTAL + 255) / 256, blk, 0, stream>>>(
        W1, W2, W3, wt1, wt2, wt3, x1b, x2b);

    // ---- layer 1 (A = fp32 x, converted in registers)
    gemm_bf16_k<true><<<gemmGrid, blk, 0, stream>>>(x, wt1, hb, NFEAT);
    gather_k<true><<<gathBlocks, blk, 0, stream>>>(hb, row_start, bsum, ep, dinv, b1, x1b);
    logits_acc_k<0><<<rowBlocks32, blk, 0, stream>>>(x1b, Wlin, blin, logits, nullptr, 0);

    // ---- layer 2
    gemm_bf16_k<false><<<gemmGrid, blk, 0, stream>>>(x1b, wt2, hb, NHID);
    gather_k<true><<<gathBlocks, blk, 0, stream>>>(hb, row_start, bsum, ep, dinv, b2, x2b);
    logits_acc_k<1><<<rowBlocks32, blk, 0, stream>>>(x2b, Wlin, blin, logits, nullptr, 1);

    // ---- layer 3 (ones edge weights) + fused log_softmax in the logits pass
    gemm_bf16_k<false><<<gemmGrid, blk, 0, stream>>>(x2b, wt3, hb, NHID);
    gather_k<false><<<gathBlocks, blk, 0, stream>>>(hb, row_start, bsum, ep3, dinv3, b3, x3b);
    logits_acc_k<2><<<rowBlocks32, blk, 0, stream>>>(x3b, Wlin, blin, logits, out, 2);
}